// Round 1
// baseline (1214.938 us; speedup 1.0000x reference)
//
#include <hip/hip_runtime.h>
#include <hip/hip_bf16.h>
#include <math.h>

// ---------------------------------------------------------------------------
// MLPConv4d: conv4d(16->64, k=3^4, s=2, p=1) + exact GELU + conv4d(64->16)
// x: [16][32][32][32][32] fp32, h: [64][16][16][16][16], out: [16][8][8][8][8]
// ---------------------------------------------------------------------------

// ---------------- weight transposes: w[co][ci][k^4] -> wt[(ci*81+k)][co] ----
__global__ void transpose_w1(const float* __restrict__ w, float* __restrict__ wt) {
    int i = blockIdx.x * 256 + threadIdx.x;
    if (i < 64 * 1296) {
        int co = i / 1296;
        int r  = i - co * 1296;   // ci*81 + k
        wt[r * 64 + co] = w[i];
    }
}

__global__ void transpose_w2(const float* __restrict__ w, float* __restrict__ wt) {
    int i = blockIdx.x * 256 + threadIdx.x;
    if (i < 16 * 5184) {
        int co = i / 5184;
        int r  = i - co * 5184;   // ci*81 + k
        wt[r * 16 + co] = w[i];
    }
}

// ---------------- conv1 + bias + GELU ---------------------------------------
// Tile: out 2x2x2x4 spatial, all 64 co. Grid 8*8*8*4 = 2048 blocks, 256 thr.
// Patch per ci: 5*5*5*9 = 1125 floats. Stage 4 ci at a time (17.6 KB LDS).
// Thread: spa = tid&31 (2x2x2x4), co group = tid>>5 (8 groups x 8 co).
constexpr int C1_P1 = 5, C1_P2 = 5, C1_P3 = 5, C1_P4 = 9;
constexpr int C1_PATCH = C1_P1 * C1_P2 * C1_P3 * C1_P4;   // 1125
constexpr int C1_CISTAGE = 4;

__global__ __launch_bounds__(256) void conv1_gelu_kernel(
        const float* __restrict__ x, const float* __restrict__ w1t,
        const float* __restrict__ b1, float* __restrict__ h) {
    __shared__ float sx[C1_CISTAGE * C1_PATCH];   // 4500 floats = 18000 B

    const int tid = threadIdx.x;
    const int bid = blockIdx.x;
    // tile decode: 8 x 8 x 8 x 4 tiles
    const int t4 = bid & 3, t3 = (bid >> 2) & 7, t2 = (bid >> 5) & 7, t1 = (bid >> 8) & 7;
    const int bo1 = t1 * 2, bo2 = t2 * 2, bo3 = t3 * 2, bo4 = t4 * 4;
    const int g1b = bo1 * 2 - 1, g2b = bo2 * 2 - 1, g3b = bo3 * 2 - 1, g4b = bo4 * 2 - 1;

    const int spa = tid & 31;
    const int o4l = spa & 3, o3l = (spa >> 2) & 1, o2l = (spa >> 3) & 1, o1l = (spa >> 4) & 1;
    const int co  = (tid >> 5) * 8;   // 8 consecutive output channels

    float acc[8];
#pragma unroll
    for (int i = 0; i < 8; ++i) acc[i] = 0.f;

    for (int st = 0; st < 16 / C1_CISTAGE; ++st) {
        // ---- stage load: rows of 9 contiguous floats (i4) ----
        // rows: ci(4) x i1(5) x i2(5) x i3(5) = 500 rows
        for (int rr = tid; rr < C1_CISTAGE * 125; rr += 256) {
            int ci = rr / 125;
            int r  = rr - ci * 125;
            int i1 = r / 25;  r -= i1 * 25;
            int i2 = r / 5;
            int i3 = r - i2 * 5;
            int g1 = g1b + i1, g2 = g2b + i2, g3 = g3b + i3;
            bool ok123 = ((unsigned)g1 < 32u) & ((unsigned)g2 < 32u) & ((unsigned)g3 < 32u);
            const float* src = x + (((((size_t)(st * C1_CISTAGE + ci) * 32 + g1) * 32 + g2) * 32 + g3) * 32 + g4b);
            float* dst = sx + rr * 9;
#pragma unroll
            for (int i4 = 0; i4 < 9; ++i4) {
                int g4 = g4b + i4;
                float v = 0.f;
                if (ok123 && (unsigned)g4 < 32u) v = src[i4];
                dst[i4] = v;
            }
        }
        __syncthreads();

        // ---- compute ----
        for (int cis = 0; cis < C1_CISTAGE; ++cis) {
            const int ci = st * C1_CISTAGE + cis;
            const float* wp = w1t + (size_t)(ci * 81) * 64 + co;
            const float* xb = sx + cis * C1_PATCH
                              + (2 * o1l) * (C1_P2 * C1_P3 * C1_P4)
                              + (2 * o2l) * (C1_P3 * C1_P4)
                              + (2 * o3l) * C1_P4
                              + 2 * o4l;
            for (int k1 = 0; k1 < 3; ++k1)
            for (int k2 = 0; k2 < 3; ++k2) {
                const float* xbb = xb + k1 * (C1_P2 * C1_P3 * C1_P4) + k2 * (C1_P3 * C1_P4);
                const float* wpp = wp + ((k1 * 3 + k2) * 9) * 64;
#pragma unroll
                for (int k3 = 0; k3 < 3; ++k3) {
#pragma unroll
                    for (int k4 = 0; k4 < 3; ++k4) {
                        float xv = xbb[k3 * C1_P4 + k4];
                        const float4 wa = *(const float4*)(wpp + (k3 * 3 + k4) * 64);
                        const float4 wb = *(const float4*)(wpp + (k3 * 3 + k4) * 64 + 4);
                        acc[0] += xv * wa.x; acc[1] += xv * wa.y;
                        acc[2] += xv * wa.z; acc[3] += xv * wa.w;
                        acc[4] += xv * wb.x; acc[5] += xv * wb.y;
                        acc[6] += xv * wb.z; acc[7] += xv * wb.w;
                    }
                }
            }
        }
        __syncthreads();
    }

    // ---- bias + exact GELU + store (h layout [co][16][16][16][16]) ----
    const int o1 = bo1 + o1l, o2 = bo2 + o2l, o3 = bo3 + o3l, o4 = bo4 + o4l;
    const size_t sp = (((size_t)o1 * 16 + o2) * 16 + o3) * 16 + o4;
#pragma unroll
    for (int c = 0; c < 8; ++c) {
        float v = acc[c] + b1[co + c];
        v = 0.5f * v * (1.f + erff(v * 0.70710678118654752f));
        h[(size_t)(co + c) * 65536 + sp] = v;
    }
}

// ---------------- conv2 + bias ----------------------------------------------
// Tile: out 2x2x2x2 spatial, all 16 co. Grid 4^4 = 256 blocks, 256 thr.
// Patch per ci: 5^4 = 625 floats. Stage 8 ci at a time (20 KB LDS).
// Thread: spa = tid&15, co = tid>>4. One output per thread.
constexpr int C2_PATCH = 625;
constexpr int C2_CISTAGE = 8;

__global__ __launch_bounds__(256) void conv2_kernel(
        const float* __restrict__ hin, const float* __restrict__ w2t,
        const float* __restrict__ b2, float* __restrict__ out) {
    __shared__ float sx[C2_CISTAGE * C2_PATCH];   // 5000 floats = 20000 B

    const int tid = threadIdx.x;
    const int bid = blockIdx.x;
    const int t4 = bid & 3, t3 = (bid >> 2) & 3, t2 = (bid >> 4) & 3, t1 = (bid >> 6) & 3;
    const int bo1 = t1 * 2, bo2 = t2 * 2, bo3 = t3 * 2, bo4 = t4 * 2;
    const int g1b = bo1 * 2 - 1, g2b = bo2 * 2 - 1, g3b = bo3 * 2 - 1, g4b = bo4 * 2 - 1;

    const int spa = tid & 15;
    const int o4l = spa & 1, o3l = (spa >> 1) & 1, o2l = (spa >> 2) & 1, o1l = (spa >> 3) & 1;
    const int co  = tid >> 4;   // 0..15

    float acc = 0.f;

    for (int st = 0; st < 64 / C2_CISTAGE; ++st) {
        // rows: ci(8) x i1(5) x i2(5) x i3(5) = 1000 rows of 5 floats
        for (int rr = tid; rr < C2_CISTAGE * 125; rr += 256) {
            int ci = rr / 125;
            int r  = rr - ci * 125;
            int i1 = r / 25;  r -= i1 * 25;
            int i2 = r / 5;
            int i3 = r - i2 * 5;
            int g1 = g1b + i1, g2 = g2b + i2, g3 = g3b + i3;
            bool ok123 = ((unsigned)g1 < 16u) & ((unsigned)g2 < 16u) & ((unsigned)g3 < 16u);
            const float* src = hin + (((((size_t)(st * C2_CISTAGE + ci) * 16 + g1) * 16 + g2) * 16 + g3) * 16 + g4b);
            float* dst = sx + rr * 5;
#pragma unroll
            for (int i4 = 0; i4 < 5; ++i4) {
                int g4 = g4b + i4;
                float v = 0.f;
                if (ok123 && (unsigned)g4 < 16u) v = src[i4];
                dst[i4] = v;
            }
        }
        __syncthreads();

        for (int cis = 0; cis < C2_CISTAGE; ++cis) {
            const int ci = st * C2_CISTAGE + cis;
            const float* wp = w2t + (size_t)(ci * 81) * 16 + co;
            const float* xb = sx + cis * C2_PATCH
                              + (2 * o1l) * 125 + (2 * o2l) * 25 + (2 * o3l) * 5 + 2 * o4l;
            for (int k1 = 0; k1 < 3; ++k1)
            for (int k2 = 0; k2 < 3; ++k2) {
                const float* xbb = xb + k1 * 125 + k2 * 25;
                const float* wpp = wp + ((k1 * 3 + k2) * 9) * 16;
#pragma unroll
                for (int k3 = 0; k3 < 3; ++k3) {
#pragma unroll
                    for (int k4 = 0; k4 < 3; ++k4) {
                        acc += xbb[k3 * 5 + k4] * wpp[(k3 * 3 + k4) * 16];
                    }
                }
            }
        }
        __syncthreads();
    }

    const int o1 = bo1 + o1l, o2 = bo2 + o2l, o3 = bo3 + o3l, o4 = bo4 + o4l;
    out[(((size_t)co * 8 + o1) * 8 + o2) * 8 * 8 + o3 * 8 + o4] = acc + b2[co];
}

// ---------------------------------------------------------------------------
extern "C" void kernel_launch(void* const* d_in, const int* in_sizes, int n_in,
                              void* d_out, int out_size, void* d_ws, size_t ws_size,
                              hipStream_t stream) {
    const float* x  = (const float*)d_in[0];
    const float* w1 = (const float*)d_in[1];
    const float* b1 = (const float*)d_in[2];
    const float* w2 = (const float*)d_in[3];
    const float* b2 = (const float*)d_in[4];
    float* out = (float*)d_out;

    float* h   = (float*)d_ws;            // 4,194,304 floats = 16 MB
    float* w1t = h + 4194304;             // 82,944 floats
    float* w2t = w1t + 82944;             // 82,944 floats

    transpose_w1<<<(64 * 1296 + 255) / 256, 256, 0, stream>>>(w1, w1t);
    transpose_w2<<<(16 * 5184 + 255) / 256, 256, 0, stream>>>(w2, w2t);
    conv1_gelu_kernel<<<2048, 256, 0, stream>>>(x, w1t, b1, h);
    conv2_kernel<<<256, 256, 0, stream>>>(h, w2t, b2, out);
}

// Round 2
// 311.820 us; speedup vs baseline: 3.8963x; 3.8963x over previous
//
#include <hip/hip_runtime.h>
#include <math.h>

// ---------------------------------------------------------------------------
// MLPConv4d: conv4d(16->64, k=3^4, s=2, p=1) + exact GELU + conv4d(64->16)
// x: [16][32^4] fp32, h: [64][16^4], out: [16][8^4]
// ---------------------------------------------------------------------------

// weight transposes: w[co][ci][k^4] -> wt[(ci*81+k)][co]
__global__ void transpose_w1(const float* __restrict__ w, float* __restrict__ wt) {
    int i = blockIdx.x * 256 + threadIdx.x;
    if (i < 64 * 1296) {
        int co = i / 1296;
        int r  = i - co * 1296;
        wt[r * 64 + co] = w[i];
    }
}

__global__ void transpose_w2(const float* __restrict__ w, float* __restrict__ wt) {
    int i = blockIdx.x * 256 + threadIdx.x;
    if (i < 16 * 5184) {
        int co = i / 5184;
        int r  = i - co * 5184;
        wt[r * 16 + co] = w[i];
    }
}

__global__ void out_init(const float* __restrict__ b2, float* __restrict__ out) {
    int i = blockIdx.x * 256 + threadIdx.x;   // 65536 total
    out[i] = b2[i >> 12];
}

// ---------------- conv1 + bias + GELU ---------------------------------------
// Block tile: spatial 2x2x4x8 (o1,o2,o3,o4) x all 64 co. Grid 8*8*4*2 = 512.
// Thread: spa=tid&31 -> (o1l,o2l,o4l); owns o3l=0..3 x 8 co = 32 acc.
// LDS x patch (1 ci): [i1 5][i2 5][i3 9][r=i4&1 2][q=i4>>1 9] = 4050 floats.
//   strides: i1:810 i2:162 i3:18 r:9 q:1.
//   lane-varying bank deltas: o4l->1, o2l->324%32=4, o1l->1620%32=20 => <=2-way.
// LDS w (1 ci): [k 81][co 64] = 5184 floats; half-wave reads broadcast.
__global__ __launch_bounds__(256) void conv1_gelu(
        const float* __restrict__ x, const float* __restrict__ w1t,
        const float* __restrict__ b1, float* __restrict__ h) {
    __shared__ float sx[4050];
    __shared__ float sw[5184];

    const int tid = threadIdx.x;
    const int bid = blockIdx.x;
    const int t4 = bid & 1, t3 = (bid >> 1) & 3, t2 = (bid >> 3) & 7, t1 = (bid >> 6) & 7;
    const int bo1 = t1 * 2, bo2 = t2 * 2, bo3 = t3 * 4, bo4 = t4 * 8;
    const int g1b = 2 * bo1 - 1, g2b = 2 * bo2 - 1, g3b = 2 * bo3 - 1, g4b = 2 * bo4 - 1;

    const int spa = tid & 31;
    const int o4l = spa & 7, o2l = (spa >> 3) & 1, o1l = (spa >> 4) & 1;
    const int co  = (tid >> 5) * 8;

    float acc[4][8] = {};
    const int xbase = o1l * 1620 + o2l * 324 + o4l;

    for (int ci = 0; ci < 16; ++ci) {
        // stage x patch: 5*5*9*17 = 3825 elements, i4-inner => coalesced global
        for (int e = tid; e < 3825; e += 256) {
            int i4 = e % 17; int r = e / 17;
            int i3 = r % 9;  r /= 9;
            int i2 = r % 5;  int i1 = r / 5;
            int g1 = g1b + i1, g2 = g2b + i2, g3 = g3b + i3, g4 = g4b + i4;
            bool ok = ((unsigned)g1 < 32u) & ((unsigned)g2 < 32u) &
                      ((unsigned)g3 < 32u) & ((unsigned)g4 < 32u);
            float v = ok ? x[((((size_t)ci * 32 + g1) * 32 + g2) * 32 + g3) * 32 + g4] : 0.f;
            sx[i1 * 810 + i2 * 162 + i3 * 18 + (i4 & 1) * 9 + (i4 >> 1)] = v;
        }
        // stage w: 5184 floats = 1296 float4, fully coalesced
        {
            const float4* src = (const float4*)(w1t + (size_t)ci * 5184);
            float4* dst = (float4*)sw;
            for (int e = tid; e < 1296; e += 256) dst[e] = src[e];
        }
        __syncthreads();

        for (int k1 = 0; k1 < 3; ++k1)
        for (int k2 = 0; k2 < 3; ++k2) {
            const float* xb = sx + xbase + k1 * 810 + k2 * 162;
            const float* wb = sw + (k1 * 3 + k2) * 576 + co;
#pragma unroll
            for (int k3 = 0; k3 < 3; ++k3)
#pragma unroll
            for (int k4 = 0; k4 < 3; ++k4) {
                const float4 wa = *(const float4*)(wb + (k3 * 3 + k4) * 64);
                const float4 wc = *(const float4*)(wb + (k3 * 3 + k4) * 64 + 4);
#pragma unroll
                for (int j = 0; j < 4; ++j) {
                    float xv = xb[(2 * j + k3) * 18 + (k4 & 1) * 9 + (k4 >> 1)];
                    acc[j][0] += xv * wa.x; acc[j][1] += xv * wa.y;
                    acc[j][2] += xv * wa.z; acc[j][3] += xv * wa.w;
                    acc[j][4] += xv * wc.x; acc[j][5] += xv * wc.y;
                    acc[j][6] += xv * wc.z; acc[j][7] += xv * wc.w;
                }
            }
        }
        __syncthreads();
    }

    // bias + exact GELU + store; lanes vary o4l => 8-wide contiguous segments
    const int o1 = bo1 + o1l, o2 = bo2 + o2l, o4 = bo4 + o4l;
#pragma unroll
    for (int j = 0; j < 4; ++j) {
        const int o3 = bo3 + j;
        const size_t sp = (((size_t)o1 * 16 + o2) * 16 + o3) * 16 + o4;
#pragma unroll
        for (int c = 0; c < 8; ++c) {
            float v = acc[j][c] + b1[co + c];
            v = 0.5f * v * (1.f + erff(v * 0.70710678118654752f));
            h[(size_t)(co + c) * 65536 + sp] = v;
        }
    }
}

// ---------------- conv2 (split-K over ci, atomic combine) -------------------
// Block: spatial tile 4x4x4x4 x 16 co, 4 ci of 64. Grid = 16 sp-tiles x 16 ci-groups.
// Thread: lan=tid&63 -> (o1l,o2l,o3l in 0..3); owns o4l=0..3 x 4 co = 16 acc.
// LDS x patch (1 ci): [i4 9][i1 9 stride85][i2 9][i3 9] = 6885 floats.
//   lane deltas: o3l->2, o2l->18, o1l->170%32=10 => low-way conflicts.
__global__ __launch_bounds__(256) void conv2_part(
        const float* __restrict__ hin, const float* __restrict__ w2t,
        float* __restrict__ out) {
    __shared__ float sx[6885];
    __shared__ float sw[1296];

    const int tid = threadIdx.x;
    const int bid = blockIdx.x;
    const int sp  = bid & 15, cig = bid >> 4;
    const int t4 = sp & 1, t3 = (sp >> 1) & 1, t2 = (sp >> 2) & 1, t1 = (sp >> 3) & 1;
    const int bo1 = t1 * 4, bo2 = t2 * 4, bo3 = t3 * 4, bo4 = t4 * 4;
    const int g1b = 2 * bo1 - 1, g2b = 2 * bo2 - 1, g3b = 2 * bo3 - 1, g4b = 2 * bo4 - 1;

    const int lan = tid & 63;
    const int o3l = lan & 3, o2l = (lan >> 2) & 3, o1l = (lan >> 4) & 3;
    const int co  = (tid >> 6) * 4;

    float acc[4][4] = {};
    const int xbase = o1l * 170 + o2l * 18 + o3l * 2;

    for (int s = 0; s < 4; ++s) {
        const int ci = cig * 4 + s;
        // stage x patch: 9^4 = 6561 elements, i4-inner
        for (int e = tid; e < 6561; e += 256) {
            int i4 = e % 9; int r = e / 9;
            int i3 = r % 9;  r /= 9;
            int i2 = r % 9;  int i1 = r / 9;
            int g1 = g1b + i1, g2 = g2b + i2, g3 = g3b + i3, g4 = g4b + i4;
            bool ok = ((unsigned)g1 < 16u) & ((unsigned)g2 < 16u) &
                      ((unsigned)g3 < 16u) & ((unsigned)g4 < 16u);
            float v = ok ? hin[((((size_t)ci * 16 + g1) * 16 + g2) * 16 + g3) * 16 + g4] : 0.f;
            sx[i4 * 765 + i1 * 85 + i2 * 9 + i3] = v;
        }
        // stage w: 81*16 = 1296 floats = 324 float4
        {
            const float4* src = (const float4*)(w2t + (size_t)ci * 1296);
            float4* dst = (float4*)sw;
            for (int e = tid; e < 324; e += 256) dst[e] = src[e];
        }
        __syncthreads();

        for (int k1 = 0; k1 < 3; ++k1)
        for (int k2 = 0; k2 < 3; ++k2) {
            const float* xb = sx + xbase + k1 * 85 + k2 * 9;
            const float* wb = sw + (k1 * 3 + k2) * 144 + co;
#pragma unroll
            for (int k3 = 0; k3 < 3; ++k3)
#pragma unroll
            for (int k4 = 0; k4 < 3; ++k4) {
                const float4 wa = *(const float4*)(wb + (k3 * 3 + k4) * 16);
#pragma unroll
                for (int j = 0; j < 4; ++j) {
                    float xv = xb[(2 * j + k4) * 765 + k3];
                    acc[j][0] += xv * wa.x; acc[j][1] += xv * wa.y;
                    acc[j][2] += xv * wa.z; acc[j][3] += xv * wa.w;
                }
            }
        }
        __syncthreads();
    }

    const int o1 = bo1 + o1l, o2 = bo2 + o2l, o3 = bo3 + o3l;
#pragma unroll
    for (int j = 0; j < 4; ++j) {
        const int o4 = bo4 + j;
#pragma unroll
        for (int c = 0; c < 4; ++c) {
            atomicAdd(&out[(size_t)(co + c) * 4096 + ((o1 * 8 + o2) * 8 + o3) * 8 + o4],
                      acc[j][c]);
        }
    }
}

// ---------------------------------------------------------------------------
extern "C" void kernel_launch(void* const* d_in, const int* in_sizes, int n_in,
                              void* d_out, int out_size, void* d_ws, size_t ws_size,
                              hipStream_t stream) {
    const float* x  = (const float*)d_in[0];
    const float* w1 = (const float*)d_in[1];
    const float* b1 = (const float*)d_in[2];
    const float* w2 = (const float*)d_in[3];
    const float* b2 = (const float*)d_in[4];
    float* out = (float*)d_out;

    float* h   = (float*)d_ws;            // 4,194,304 floats = 16 MB
    float* w1t = h + 4194304;             // 82,944 floats
    float* w2t = w1t + 82944;             // 82,944 floats

    transpose_w1<<<(64 * 1296 + 255) / 256, 256, 0, stream>>>(w1, w1t);
    transpose_w2<<<(16 * 5184 + 255) / 256, 256, 0, stream>>>(w2, w2t);
    out_init<<<256, 256, 0, stream>>>(b2, out);
    conv1_gelu<<<512, 256, 0, stream>>>(x, w1t, b1, h);
    conv2_part<<<256, 256, 0, stream>>>(h, w2t, out);
}

// Round 3
// 250.114 us; speedup vs baseline: 4.8575x; 1.2467x over previous
//
#include <hip/hip_runtime.h>
#include <hip/hip_bf16.h>
#include <math.h>

// ---------------------------------------------------------------------------
// MLPConv4d via bf16 MFMA implicit GEMM.
// conv1: x[16][32^4] fp32 -> hpad[64][18^4] bf16 (GELU'd, zero shell)
// conv2: hpad -> out[16][8^4] fp32 (split-K atomics onto bias-init'd out)
// K-dim layout: k' = grp*4 + k4 (grp=(k1*3+k2)*3+k3 <27, k4<3 real; slot 3 and
// k'>=108 are ZERO in the prepacked weights; B pad slots kept finite).
// B-tile LDS: [128 sp][136 k'] bf16, phys byte = logical ^ (((sp>>3)&7)<<4).
// ---------------------------------------------------------------------------

typedef __attribute__((ext_vector_type(8))) short short8;
typedef __attribute__((ext_vector_type(4))) float f32x4;
typedef __attribute__((ext_vector_type(4))) unsigned int uint4v;

__device__ __forceinline__ unsigned short f2bf(float v) {
    __hip_bfloat16 b = __float2bfloat16(v);
    return *(unsigned short*)&b;
}

// ---- prepack: w1[co 64][ci 16][81] -> w1p[ci][co][136] bf16 (zero-padded) --
__global__ void prepack_w1(const float* __restrict__ w, unsigned short* __restrict__ wp) {
    int i = blockIdx.x * 256 + threadIdx.x;
    if (i >= 16 * 64 * 136) return;
    int kp = i % 136;
    int co = (i / 136) % 64;
    int ci = i / (136 * 64);
    float v = 0.f;
    if (kp < 108 && (kp & 3) < 3) {
        int k = (kp >> 2) * 3 + (kp & 3);
        v = w[(co * 16 + ci) * 81 + k];
    }
    wp[i] = f2bf(v);
}

// ---- prepack: w2[co 16][ci 64][81] -> w2p[ci][co][136] bf16 ---------------
__global__ void prepack_w2(const float* __restrict__ w, unsigned short* __restrict__ wp) {
    int i = blockIdx.x * 256 + threadIdx.x;
    if (i >= 64 * 16 * 136) return;
    int kp = i % 136;
    int co = (i / 136) % 16;
    int ci = i / (136 * 16);
    float v = 0.f;
    if (kp < 108 && (kp & 3) < 3) {
        int k = (kp >> 2) * 3 + (kp & 3);
        v = w[(co * 64 + ci) * 81 + k];
    }
    wp[i] = f2bf(v);
}

__global__ void zero_hpad(uint4v* __restrict__ p) {
    for (int i = blockIdx.x * 256 + threadIdx.x; i < 839808; i += 1024 * 256)
        p[i] = (uint4v){0, 0, 0, 0};
}

__global__ void out_init(const float* __restrict__ b2, float* __restrict__ out) {
    int i = blockIdx.x * 256 + threadIdx.x;   // 65536
    out[i] = b2[i >> 12];
}

// ---------------- conv1: MFMA, GELU epilogue --------------------------------
// Block: sp-tile 128 = (o1,o2,o3,o4)=(2,2,4,8), all 64 co. Grid 512.
// Footprint LDS [5][5][9][18] bf16 (strides 810/162/18/1); i4=17 col zeroed.
__global__ __launch_bounds__(256) void conv1_mfma(
        const float* __restrict__ x, const unsigned short* __restrict__ w1p,
        const float* __restrict__ b1, unsigned short* __restrict__ hpad) {
    __shared__ unsigned short sF[4050];
    __shared__ unsigned short sB[17408];   // 128*136
    __shared__ int sktab[28];

    const int tid = threadIdx.x;
    const int bid = blockIdx.x;
    const int t4 = bid & 1, t3 = (bid >> 1) & 3, t2 = (bid >> 3) & 7, t1 = bid >> 6;
    const int bo1 = 2 * t1, bo2 = 2 * t2, bo3 = 4 * t3, bo4 = 8 * t4;
    const int g1b = 2 * bo1 - 1, g2b = 2 * bo2 - 1, g3b = 2 * bo3 - 1, g4b = 2 * bo4 - 1;

    // init: ktable (fp word-offset per kernel group; [27] aliases [26] = finite)
    if (tid < 28) {
        int g = tid < 27 ? tid : 26;
        int k1 = g / 9, k2 = (g / 3) % 3, k3 = g % 3;
        sktab[tid] = k1 * 810 + k2 * 162 + k3 * 18;
    }
    if (tid < 225) sF[tid * 18 + 17] = 0;          // pad column (finite for 4th slot)
    // zero B k' in [112,128): group-pairs 14,15
    {
        int sp_ = tid & 127, g0_ = tid >> 7;
        int K_ = ((sp_ >> 3) & 7) << 4;
        *(uint4v*)((char*)sB + ((sp_ * 272 + (14 + g0_) * 16) ^ K_)) = (uint4v){0, 0, 0, 0};
    }

    // staging row (fixed per thread): 225 rows of 17 i4-elems
    int i1 = 0, i2 = 0, i3 = 0;
    bool rowv = false;
    int rowbase = 0;
    if (tid < 225) {
        i1 = tid / 45; i2 = (tid / 9) % 5; i3 = tid % 9;
        int g1 = g1b + i1, g2 = g2b + i2, g3 = g3b + i3;
        rowv = ((unsigned)g1 < 32u) & ((unsigned)g2 < 32u) & ((unsigned)g3 < 32u);
        rowbase = g1 * 32768 + g2 * 1024 + g3 * 32;
    }
    unsigned short* dstrow = sF + (i1 * 810 + i2 * 162 + i3 * 18);

    // expand constants
    const int sp = tid & 127, g0 = tid >> 7;
    const int o4l = sp & 7, o3l = (sp >> 3) & 3, o2l = (sp >> 5) & 1, o1l = sp >> 6;
    const int fpbase = o1l * 1620 + o2l * 324 + o3l * 36 + o4l * 2;
    const int wkey = ((sp >> 3) & 7) << 4;
    const int wbase = sp * 272;

    // mfma constants
    const int lane = tid & 63, wv = tid >> 6;
    const int n16 = lane & 15, hi = lane >> 4;
    const int n8 = n16 >> 3;
    const int bbase = n16 * 272 + hi * 16;
    const int cobase = 16 * wv;

    f32x4 zero4 = {0.f, 0.f, 0.f, 0.f};
    f32x4 acc[8];
#pragma unroll
    for (int t = 0; t < 8; ++t) acc[t] = zero4;

    __syncthreads();

    for (int ci = 0; ci < 16; ++ci) {
        // A fragments from global (L2-resident prepacked weights)
        const unsigned short* aw = w1p + (ci * 64 + cobase + n16) * 136 + hi * 8;
        short8 a0 = *(const short8*)(aw);
        short8 a1 = *(const short8*)(aw + 32);
        short8 a2 = *(const short8*)(aw + 64);
        short8 a3 = *(const short8*)(aw + 96);

        // stage footprint (fp32 global -> bf16 LDS), bounds-checked
        if (tid < 225) {
            const float* xr = x + ci * 1048576 + rowbase + g4b;
            unsigned short u[17];
#pragma unroll
            for (int j = 0; j < 17; ++j) {
                int g4 = g4b + j;
                float v = (rowv && (unsigned)g4 < 32u) ? xr[j] : 0.f;
                u[j] = f2bf(v);
            }
#pragma unroll
            for (int p = 0; p < 8; ++p)
                *(unsigned*)(dstrow + 2 * p) = (unsigned)u[2 * p] | ((unsigned)u[2 * p + 1] << 16);
            dstrow[16] = u[16];
        }
        __syncthreads();

        // expand im2col: per group-pair gp, 4 LDS word reads -> 1 b128 swizzled write
        for (int gp = g0; gp < 14; gp += 2) {
            int j0 = fpbase + sktab[2 * gp];
            int j1 = fpbase + sktab[2 * gp + 1];
            unsigned w0 = *(const unsigned*)((const char*)sF + 2 * j0);
            unsigned w1_ = *(const unsigned*)((const char*)sF + 2 * j0 + 4);
            unsigned w2_ = *(const unsigned*)((const char*)sF + 2 * j1);
            unsigned w3_ = *(const unsigned*)((const char*)sF + 2 * j1 + 4);
            *(uint4v*)((char*)sB + ((wbase + gp * 16) ^ wkey)) = (uint4v){w0, w1_, w2_, w3_};
        }
        __syncthreads();

        // MFMA sweep: 8 sp-tiles x 4 K-steps
#pragma unroll
        for (int t = 0; t < 8; ++t) {
            const int tb = bbase + t * 4352;
            const int xv = ((((2 * t) & 7) + n8) << 4);
            short8 b0 = *(const short8*)((const char*)sB + ((tb + 0)   ^ xv));
            short8 b1f = *(const short8*)((const char*)sB + ((tb + 64) ^ xv));
            short8 b2f = *(const short8*)((const char*)sB + ((tb + 128) ^ xv));
            short8 b3f = *(const short8*)((const char*)sB + ((tb + 192) ^ xv));
            acc[t] = __builtin_amdgcn_mfma_f32_16x16x32_bf16(a0, b0, acc[t], 0, 0, 0);
            acc[t] = __builtin_amdgcn_mfma_f32_16x16x32_bf16(a1, b1f, acc[t], 0, 0, 0);
            acc[t] = __builtin_amdgcn_mfma_f32_16x16x32_bf16(a2, b2f, acc[t], 0, 0, 0);
            acc[t] = __builtin_amdgcn_mfma_f32_16x16x32_bf16(a3, b3f, acc[t], 0, 0, 0);
        }
        __syncthreads();
    }

    // epilogue: bias + exact GELU + bf16 store into padded h
    float bv[4];
#pragma unroll
    for (int r = 0; r < 4; ++r) bv[r] = b1[cobase + hi * 4 + r];
#pragma unroll
    for (int t = 0; t < 8; ++t) {
        int spl = 16 * t + n16;
        int e4 = spl & 7, e3 = (spl >> 3) & 3, e2 = (spl >> 5) & 1, e1 = spl >> 6;
        size_t base = (size_t)(bo1 + e1 + 1) * 5832 + (bo2 + e2 + 1) * 324 +
                      (bo3 + e3 + 1) * 18 + (bo4 + e4 + 1);
#pragma unroll
        for (int r = 0; r < 4; ++r) {
            int co = cobase + hi * 4 + r;
            float v = acc[t][r] + bv[r];
            v = 0.5f * v * (1.f + erff(v * 0.70710678118654752f));
            hpad[(size_t)co * 104976 + base] = f2bf(v);
        }
    }
}

// ---------------- conv2: MFMA, split-K atomics ------------------------------
// Block: sp-tile 128 = (2,2,4,8) over out 8^4 (32 tiles) x 8 ci. Grid 256.
__global__ __launch_bounds__(256) void conv2_mfma(
        const unsigned short* __restrict__ hpad, const unsigned short* __restrict__ w2p,
        float* __restrict__ out) {
    __shared__ unsigned short sF[4050];
    __shared__ unsigned short sB[17408];
    __shared__ int sktab[28];

    const int tid = threadIdx.x;
    const int bid = blockIdx.x;
    const int s = bid & 31, cig = bid >> 5;
    const int bo1 = 2 * ((s >> 3) & 3), bo2 = 2 * ((s >> 1) & 3), bo3 = 4 * (s & 1);

    if (tid < 28) {
        int g = tid < 27 ? tid : 26;
        int k1 = g / 9, k2 = (g / 3) % 3, k3 = g % 3;
        sktab[tid] = k1 * 810 + k2 * 162 + k3 * 18;
    }
    if (tid < 225) sF[tid * 18 + 17] = 0;
    {
        int sp_ = tid & 127, g0_ = tid >> 7;
        int K_ = ((sp_ >> 3) & 7) << 4;
        *(uint4v*)((char*)sB + ((sp_ * 272 + (14 + g0_) * 16) ^ K_)) = (uint4v){0, 0, 0, 0};
    }

    // staging rows: hpad indices g_d = 2*bo_d + i_d, always in bounds
    int rowoff = 0;
    if (tid < 225) {
        int i1 = tid / 45, i2 = (tid / 9) % 5, i3 = tid % 9;
        rowoff = (2 * bo1 + i1) * 5832 + (2 * bo2 + i2) * 324 + (2 * bo3 + i3) * 18;
    }
    int i1_ = tid < 225 ? tid / 45 : 0, i2_ = tid < 225 ? (tid / 9) % 5 : 0, i3_ = tid < 225 ? tid % 9 : 0;
    unsigned short* dstrow = sF + (i1_ * 810 + i2_ * 162 + i3_ * 18);

    const int sp = tid & 127, g0 = tid >> 7;
    const int o4l = sp & 7, o3l = (sp >> 3) & 3, o2l = (sp >> 5) & 1, o1l = sp >> 6;
    const int fpbase = o1l * 1620 + o2l * 324 + o3l * 36 + o4l * 2;
    const int wkey = ((sp >> 3) & 7) << 4;
    const int wbase = sp * 272;

    const int lane = tid & 63, wv = tid >> 6;
    const int n16 = lane & 15, hi = lane >> 4;
    const int n8 = n16 >> 3;
    const int bbase = n16 * 272 + hi * 16;

    f32x4 zero4 = {0.f, 0.f, 0.f, 0.f};
    f32x4 acc[2];
    acc[0] = zero4; acc[1] = zero4;

    __syncthreads();

    for (int s8 = 0; s8 < 8; ++s8) {
        const int ci = cig * 8 + s8;
        const unsigned short* aw = w2p + (ci * 16 + n16) * 136 + hi * 8;
        short8 a0 = *(const short8*)(aw);
        short8 a1 = *(const short8*)(aw + 32);
        short8 a2 = *(const short8*)(aw + 64);
        short8 a3 = *(const short8*)(aw + 96);

        if (tid < 225) {
            const unsigned short* hr = hpad + (size_t)ci * 104976 + rowoff;
#pragma unroll
            for (int p = 0; p < 8; ++p)
                *(unsigned*)(dstrow + 2 * p) = *(const unsigned*)(hr + 2 * p);
            dstrow[16] = hr[16];
        }
        __syncthreads();

        for (int gp = g0; gp < 14; gp += 2) {
            int j0 = fpbase + sktab[2 * gp];
            int j1 = fpbase + sktab[2 * gp + 1];
            unsigned w0 = *(const unsigned*)((const char*)sF + 2 * j0);
            unsigned w1_ = *(const unsigned*)((const char*)sF + 2 * j0 + 4);
            unsigned w2_ = *(const unsigned*)((const char*)sF + 2 * j1);
            unsigned w3_ = *(const unsigned*)((const char*)sF + 2 * j1 + 4);
            *(uint4v*)((char*)sB + ((wbase + gp * 16) ^ wkey)) = (uint4v){w0, w1_, w2_, w3_};
        }
        __syncthreads();

#pragma unroll
        for (int t = 0; t < 2; ++t) {
            const int T = 2 * wv + t;
            const int tb = bbase + T * 4352;
            const int xv = ((((2 * T) & 7) + n8) << 4);
            short8 b0 = *(const short8*)((const char*)sB + ((tb + 0)   ^ xv));
            short8 b1f = *(const short8*)((const char*)sB + ((tb + 64) ^ xv));
            short8 b2f = *(const short8*)((const char*)sB + ((tb + 128) ^ xv));
            short8 b3f = *(const short8*)((const char*)sB + ((tb + 192) ^ xv));
            acc[t] = __builtin_amdgcn_mfma_f32_16x16x32_bf16(a0, b0, acc[t], 0, 0, 0);
            acc[t] = __builtin_amdgcn_mfma_f32_16x16x32_bf16(a1, b1f, acc[t], 0, 0, 0);
            acc[t] = __builtin_amdgcn_mfma_f32_16x16x32_bf16(a2, b2f, acc[t], 0, 0, 0);
            acc[t] = __builtin_amdgcn_mfma_f32_16x16x32_bf16(a3, b3f, acc[t], 0, 0, 0);
        }
        __syncthreads();
    }

#pragma unroll
    for (int t = 0; t < 2; ++t) {
        int spl = 16 * (2 * wv + t) + n16;
        int e4 = spl & 7, e3 = (spl >> 3) & 3, e2 = (spl >> 5) & 1, e1 = spl >> 6;
        int o1 = bo1 + e1, o2 = bo2 + e2, o3 = bo3 + e3, o4 = e4;
#pragma unroll
        for (int r = 0; r < 4; ++r) {
            int co = hi * 4 + r;
            atomicAdd(&out[(size_t)co * 4096 + (size_t)o1 * 512 + o2 * 64 + o3 * 8 + o4],
                      acc[t][r]);
        }
    }
}

// ---------------------------------------------------------------------------
extern "C" void kernel_launch(void* const* d_in, const int* in_sizes, int n_in,
                              void* d_out, int out_size, void* d_ws, size_t ws_size,
                              hipStream_t stream) {
    const float* x  = (const float*)d_in[0];
    const float* w1 = (const float*)d_in[1];
    const float* b1 = (const float*)d_in[2];
    const float* w2 = (const float*)d_in[3];
    const float* b2 = (const float*)d_in[4];
    float* out = (float*)d_out;

    unsigned short* hpad = (unsigned short*)d_ws;        // 64*18^4 = 6,718,464 bf16
    unsigned short* w1p  = hpad + 6718464;               // 139,264 bf16
    unsigned short* w2p  = w1p + 139264;                 // 139,264 bf16

    prepack_w1<<<(16 * 64 * 136 + 255) / 256, 256, 0, stream>>>(w1, w1p);
    prepack_w2<<<(64 * 16 * 136 + 255) / 256, 256, 0, stream>>>(w2, w2p);
    zero_hpad<<<1024, 256, 0, stream>>>((uint4v*)hpad);
    out_init<<<256, 256, 0, stream>>>(b2, out);
    conv1_mfma<<<512, 256, 0, stream>>>(x, w1p, b1, hpad);
    conv2_mfma<<<256, 256, 0, stream>>>(hpad, w2p, out);
}

// Round 4
// 119.096 us; speedup vs baseline: 10.2013x; 2.1001x over previous
//
#include <hip/hip_runtime.h>
#include <hip/hip_bf16.h>
#include <math.h>

// ---------------------------------------------------------------------------
// MLPConv4d via bf16 MFMA implicit GEMM (pipelined v2).
// conv1: x[16][32^4] fp32 -> hpad[64][18^4] bf16 (GELU'd, zero shell)
// conv2: hpad -> out[16][8^4] fp32 (split-K atomics onto bias-init'd out)
// K layout: k' = grp*4 + k4 (grp<27; k4=3 slot and k'>=108 are zero WEIGHTS;
// B pad slots finite). B-tile LDS [128 sp][136 k'], byte ^= ((sp>>3)&7)<<4.
// ---------------------------------------------------------------------------

typedef __attribute__((ext_vector_type(8))) short short8;
typedef __attribute__((ext_vector_type(4))) float f32x4;
typedef __attribute__((ext_vector_type(4))) unsigned int uint4v;

__device__ __forceinline__ unsigned short f2bf(float v) {
    __hip_bfloat16 b = __float2bfloat16(v);
    return *(unsigned short*)&b;
}

// ---- prepack: w1[co 64][ci 16][81] -> w1p[ci][co][136] bf16 (zero-padded) --
__global__ void prepack_w1(const float* __restrict__ w, unsigned short* __restrict__ wp) {
    int i = blockIdx.x * 256 + threadIdx.x;
    if (i >= 16 * 64 * 136) return;
    int kp = i % 136;
    int co = (i / 136) % 64;
    int ci = i / (136 * 64);
    float v = 0.f;
    if (kp < 108 && (kp & 3) < 3) {
        int k = (kp >> 2) * 3 + (kp & 3);
        v = w[(co * 16 + ci) * 81 + k];
    }
    wp[i] = f2bf(v);
}

__global__ void prepack_w2(const float* __restrict__ w, unsigned short* __restrict__ wp) {
    int i = blockIdx.x * 256 + threadIdx.x;
    if (i >= 64 * 16 * 136) return;
    int kp = i % 136;
    int co = (i / 136) % 16;
    int ci = i / (136 * 16);
    float v = 0.f;
    if (kp < 108 && (kp & 3) < 3) {
        int k = (kp >> 2) * 3 + (kp & 3);
        v = w[(co * 64 + ci) * 81 + k];
    }
    wp[i] = f2bf(v);
}

__global__ void zero_hpad(uint4v* __restrict__ p) {
    for (int i = blockIdx.x * 256 + threadIdx.x; i < 839808; i += 1024 * 256)
        p[i] = (uint4v){0, 0, 0, 0};
}

__global__ void out_init(const float* __restrict__ b2, float* __restrict__ out) {
    int i = blockIdx.x * 256 + threadIdx.x;   // 65536
    out[i] = b2[i >> 12];
}

// ---------------- conv1: pipelined MFMA + GELU epilogue ----------------------
// Block: sp-tile 128 = (o1,o2,o3,o4)=(2,2,4,8), 64 co. Grid 512, 256 thr.
// Per ci: [write regs->sF] B1 [A loads + nf prefetch + expand sF->sB] B2 [MFMA].
// Wave wv: co-tiles {2(wv&1), +1}, sp-tiles (wv>>1)*4 .. +3  (B-frags shared
// across 2 co-tiles -> 16 ds_read_b128 feed 32 MFMAs per ci).
__global__ __launch_bounds__(256) void conv1_mfma(
        const float* __restrict__ x, const unsigned short* __restrict__ w1p,
        const float* __restrict__ b1, unsigned short* __restrict__ hpad) {
    __shared__ unsigned short sF[4050];    // footprint [5][5][9][18]
    __shared__ unsigned short sB[17408];   // B tile 128x136

    const int tid = threadIdx.x;
    const int bid = blockIdx.x;
    const int t4 = bid & 1, t3 = (bid >> 1) & 3, t2 = (bid >> 3) & 7, t1 = bid >> 6;
    const int bo1 = 2 * t1, bo2 = 2 * t2, bo3 = 4 * t3, bo4 = 8 * t4;
    const int g1b = 2 * bo1 - 1, g2b = 2 * bo2 - 1, g3b = 2 * bo3 - 1, g4b = 2 * bo4 - 1;

    // one-time LDS zeros (first consumers are after B1/B2 of iteration 0)
    if (tid < 225) sF[tid * 18 + 17] = 0;                     // pad column
    {
        int sp_ = tid & 127, g0_ = tid >> 7;
        int K_ = ((sp_ >> 3) & 7) << 4;
        *(uint4v*)((char*)sB + ((sp_ * 272 + (14 + g0_) * 16) ^ K_)) = (uint4v){0, 0, 0, 0};
    }

    // ---- staging slots (precomputed once): e = tid + 256*r, e < 3825 ----
    int off[15], lidx[15];
    unsigned vmask = 0;
#pragma unroll
    for (int r = 0; r < 15; ++r) {
        int e = tid + 256 * r;
        int ee = e < 3825 ? e : 0;
        int i4 = ee % 17; int q = ee / 17;
        int i3 = q % 9; q /= 9;
        int i2 = q % 5; int i1 = q / 5;
        int g1 = g1b + i1, g2 = g2b + i2, g3 = g3b + i3, g4 = g4b + i4;
        bool ok = (e < 3825) & ((unsigned)g1 < 32u) & ((unsigned)g2 < 32u) &
                  ((unsigned)g3 < 32u) & ((unsigned)g4 < 32u);
        if (ok) vmask |= (1u << r);
        off[r] = ok ? ((g1 * 32 + g2) * 32 + g3) * 32 + g4 : 0;
        lidx[r] = i1 * 810 + i2 * 162 + i3 * 18 + i4;
    }

    // ---- expand constants (register sktab, ci-invariant byte addresses) ----
    const int sp = tid & 127, g0 = tid >> 7;
    const int o4l = sp & 7, o3l = (sp >> 3) & 3, o2l = (sp >> 5) & 1, o1l = sp >> 6;
    const int fpbase = o1l * 1620 + o2l * 324 + o3l * 36 + o4l * 2;
    const int wkey = ((sp >> 3) & 7) << 4;
    const int wbase = sp * 272;

    int rba[7], rbb[7], wba[7];
#pragma unroll
    for (int i = 0; i < 7; ++i) {
        int gp = g0 + 2 * i;
        int ga = 2 * gp, gb = 2 * gp + 1;
        if (gb > 26) gb = 26;                     // alias; killed by zero weights
        rba[i] = 2 * (fpbase + (ga / 9) * 810 + ((ga / 3) % 3) * 162 + (ga % 3) * 18);
        rbb[i] = 2 * (fpbase + (gb / 9) * 810 + ((gb / 3) % 3) * 162 + (gb % 3) * 18);
        wba[i] = (wbase + gp * 16) ^ wkey;
    }

    // ---- mfma constants ----
    const int lane = tid & 63, wv = tid >> 6;
    const int n16 = lane & 15, hi = lane >> 4;
    const int n8 = n16 >> 3;
    const int bbase = n16 * 272 + hi * 16;
    const int c0 = 2 * (wv & 1);          // co-tiles c0, c0+1 (16 co each)
    const int shalf = (wv >> 1) * 4;      // sp-tiles shalf .. shalf+3

    // ---- prologue: stage ci=0 into registers ----
    unsigned short fv[15];
#pragma unroll
    for (int r = 0; r < 15; ++r) {
        float v = x[off[r]];
        v = ((vmask >> r) & 1) ? v : 0.f;
        fv[r] = f2bf(v);
    }

    f32x4 acc[2][4];
#pragma unroll
    for (int c = 0; c < 2; ++c)
#pragma unroll
    for (int t = 0; t < 4; ++t) acc[c][t] = (f32x4){0.f, 0.f, 0.f, 0.f};

    for (int ci = 0; ci < 16; ++ci) {
        // phase 1: staged regs -> sF
#pragma unroll
        for (int r = 0; r < 14; ++r) sF[lidx[r]] = fv[r];
        if (tid < 241) sF[lidx[14]] = fv[14];
        __syncthreads();   // B1: sF ready; prev MFMA done -> sB writable

        // A-frags for this ci (L2-resident prepacked weights)
        const unsigned short* aw0 = w1p + (size_t)(ci * 64 + 16 * c0 + n16) * 136 + hi * 8;
        short8 a00 = *(const short8*)(aw0);
        short8 a01 = *(const short8*)(aw0 + 32);
        short8 a02 = *(const short8*)(aw0 + 64);
        short8 a03 = *(const short8*)(aw0 + 96);
        const unsigned short* aw1 = aw0 + 16 * 136;
        short8 a10 = *(const short8*)(aw1);
        short8 a11 = *(const short8*)(aw1 + 32);
        short8 a12 = *(const short8*)(aw1 + 64);
        short8 a13 = *(const short8*)(aw1 + 96);

        // prefetch next-ci footprint into registers (coalesced)
        unsigned short nf[15];
        if (ci < 15) {
            const float* xc = x + (size_t)(ci + 1) * 1048576;
#pragma unroll
            for (int r = 0; r < 15; ++r) {
                float v = xc[off[r]];
                v = ((vmask >> r) & 1) ? v : 0.f;
                nf[r] = f2bf(v);
            }
        }

        // expand im2col: footprint -> B tile (swizzled b128 writes)
#pragma unroll
        for (int i = 0; i < 7; ++i) {
            unsigned w0  = *(const unsigned*)((const char*)sF + rba[i]);
            unsigned w1_ = *(const unsigned*)((const char*)sF + rba[i] + 4);
            unsigned w2_ = *(const unsigned*)((const char*)sF + rbb[i]);
            unsigned w3_ = *(const unsigned*)((const char*)sF + rbb[i] + 4);
            *(uint4v*)((char*)sB + wba[i]) = (uint4v){w0, w1_, w2_, w3_};
        }
        __syncthreads();   // B2: sB ready

        // MFMA: 4 sp-tiles x (2 co-tiles x 4 K-steps); B-frags shared by co
#pragma unroll
        for (int tt = 0; tt < 4; ++tt) {
            const int t = shalf + tt;
            const int tb = bbase + t * 4352;
            const int xv = ((((2 * t) & 7) + n8) << 4);
            short8 b0  = *(const short8*)((const char*)sB + ((tb + 0)   ^ xv));
            short8 b1f = *(const short8*)((const char*)sB + ((tb + 64)  ^ xv));
            short8 b2f = *(const short8*)((const char*)sB + ((tb + 128) ^ xv));
            short8 b3f = *(const short8*)((const char*)sB + ((tb + 192) ^ xv));
            acc[0][tt] = __builtin_amdgcn_mfma_f32_16x16x32_bf16(a00, b0,  acc[0][tt], 0, 0, 0);
            acc[0][tt] = __builtin_amdgcn_mfma_f32_16x16x32_bf16(a01, b1f, acc[0][tt], 0, 0, 0);
            acc[0][tt] = __builtin_amdgcn_mfma_f32_16x16x32_bf16(a02, b2f, acc[0][tt], 0, 0, 0);
            acc[0][tt] = __builtin_amdgcn_mfma_f32_16x16x32_bf16(a03, b3f, acc[0][tt], 0, 0, 0);
            acc[1][tt] = __builtin_amdgcn_mfma_f32_16x16x32_bf16(a10, b0,  acc[1][tt], 0, 0, 0);
            acc[1][tt] = __builtin_amdgcn_mfma_f32_16x16x32_bf16(a11, b1f, acc[1][tt], 0, 0, 0);
            acc[1][tt] = __builtin_amdgcn_mfma_f32_16x16x32_bf16(a12, b2f, acc[1][tt], 0, 0, 0);
            acc[1][tt] = __builtin_amdgcn_mfma_f32_16x16x32_bf16(a13, b3f, acc[1][tt], 0, 0, 0);
        }

        if (ci < 15) {
#pragma unroll
            for (int r = 0; r < 15; ++r) fv[r] = nf[r];
        }
    }

    // ---- epilogue: bias + exact GELU + bf16 store into padded h ----
#pragma unroll
    for (int cc = 0; cc < 2; ++cc) {
        float bv[4];
#pragma unroll
        for (int r = 0; r < 4; ++r) bv[r] = b1[16 * (c0 + cc) + hi * 4 + r];
#pragma unroll
        for (int tt = 0; tt < 4; ++tt) {
            int spl = 16 * (shalf + tt) + n16;
            int e4 = spl & 7, e3 = (spl >> 3) & 3, e2 = (spl >> 5) & 1, e1 = spl >> 6;
            size_t base = (size_t)(bo1 + e1 + 1) * 5832 + (bo2 + e2 + 1) * 324 +
                          (bo3 + e3 + 1) * 18 + (bo4 + e4 + 1);
#pragma unroll
            for (int r = 0; r < 4; ++r) {
                int co = 16 * (c0 + cc) + hi * 4 + r;
                float v = acc[cc][tt][r] + bv[r];
                v = 0.5f * v * (1.f + erff(v * 0.70710678118654752f));
                hpad[(size_t)co * 104976 + base] = f2bf(v);
            }
        }
    }
}

// ---------------- conv2: pipelined MFMA, split-K atomics --------------------
// Block: sp-tile 128 = (2,2,4,8) over out 8^4 (32 tiles) x 16 ci-groups (4 ci).
// Grid 512. Wave wv: sp-tiles {2wv, 2wv+1}, all 16 co.
__global__ __launch_bounds__(256) void conv2_mfma(
        const unsigned short* __restrict__ hpad, const unsigned short* __restrict__ w2p,
        float* __restrict__ out) {
    __shared__ unsigned short sF[4050];
    __shared__ unsigned short sB[17408];

    const int tid = threadIdx.x;
    const int bid = blockIdx.x;
    const int s = bid & 31, cig = bid >> 5;
    const int bo1 = 2 * ((s >> 3) & 3), bo2 = 2 * ((s >> 1) & 3), bo3 = 4 * (s & 1);

    if (tid < 225) sF[tid * 18 + 17] = 0;
    {
        int sp_ = tid & 127, g0_ = tid >> 7;
        int K_ = ((sp_ >> 3) & 7) << 4;
        *(uint4v*)((char*)sB + ((sp_ * 272 + (14 + g0_) * 16) ^ K_)) = (uint4v){0, 0, 0, 0};
    }

    // staging slots: hpad is zero-padded -> no masks
    int off[15], lidx[15];
#pragma unroll
    for (int r = 0; r < 15; ++r) {
        int e = tid + 256 * r;
        int ee = e < 3825 ? e : 0;
        int i4 = ee % 17; int q = ee / 17;
        int i3 = q % 9; q /= 9;
        int i2 = q % 5; int i1 = q / 5;
        off[r] = (2 * bo1 + i1) * 5832 + (2 * bo2 + i2) * 324 + (2 * bo3 + i3) * 18 + i4;
        lidx[r] = i1 * 810 + i2 * 162 + i3 * 18 + i4;
    }

    const int sp = tid & 127, g0 = tid >> 7;
    const int o4l = sp & 7, o3l = (sp >> 3) & 3, o2l = (sp >> 5) & 1, o1l = sp >> 6;
    const int fpbase = o1l * 1620 + o2l * 324 + o3l * 36 + o4l * 2;
    const int wkey = ((sp >> 3) & 7) << 4;
    const int wbase = sp * 272;

    int rba[7], rbb[7], wba[7];
#pragma unroll
    for (int i = 0; i < 7; ++i) {
        int gp = g0 + 2 * i;
        int ga = 2 * gp, gb = 2 * gp + 1;
        if (gb > 26) gb = 26;
        rba[i] = 2 * (fpbase + (ga / 9) * 810 + ((ga / 3) % 3) * 162 + (ga % 3) * 18);
        rbb[i] = 2 * (fpbase + (gb / 9) * 810 + ((gb / 3) % 3) * 162 + (gb % 3) * 18);
        wba[i] = (wbase + gp * 16) ^ wkey;
    }

    const int lane = tid & 63, wv = tid >> 6;
    const int n16 = lane & 15, hi = lane >> 4;
    const int n8 = n16 >> 3;
    const int bbase = n16 * 272 + hi * 16;

    unsigned short fv[15];
    {
        const unsigned short* hc = hpad + (size_t)(cig * 4) * 104976;
#pragma unroll
        for (int r = 0; r < 15; ++r) fv[r] = hc[off[r]];
    }

    f32x4 acc[2];
    acc[0] = (f32x4){0.f, 0.f, 0.f, 0.f};
    acc[1] = (f32x4){0.f, 0.f, 0.f, 0.f};

    for (int s8 = 0; s8 < 4; ++s8) {
        const int ci = cig * 4 + s8;
#pragma unroll
        for (int r = 0; r < 14; ++r) sF[lidx[r]] = fv[r];
        if (tid < 241) sF[lidx[14]] = fv[14];
        __syncthreads();   // B1

        const unsigned short* aw = w2p + (size_t)(ci * 16 + n16) * 136 + hi * 8;
        short8 a0 = *(const short8*)(aw);
        short8 a1 = *(const short8*)(aw + 32);
        short8 a2 = *(const short8*)(aw + 64);
        short8 a3 = *(const short8*)(aw + 96);

        unsigned short nf[15];
        if (s8 < 3) {
            const unsigned short* hc = hpad + (size_t)(ci + 1) * 104976;
#pragma unroll
            for (int r = 0; r < 15; ++r) nf[r] = hc[off[r]];
        }

#pragma unroll
        for (int i = 0; i < 7; ++i) {
            unsigned w0  = *(const unsigned*)((const char*)sF + rba[i]);
            unsigned w1_ = *(const unsigned*)((const char*)sF + rba[i] + 4);
            unsigned w2_ = *(const unsigned*)((const char*)sF + rbb[i]);
            unsigned w3_ = *(const unsigned*)((const char*)sF + rbb[i] + 4);
            *(uint4v*)((char*)sB + wba[i]) = (uint4v){w0, w1_, w2_, w3_};
        }
        __syncthreads();   // B2

#pragma unroll
        for (int tt = 0; tt < 2; ++tt) {
            const int T = 2 * wv + tt;
            const int tb = bbase + T * 4352;
            const int xv = ((((2 * T) & 7) + n8) << 4);
            short8 b0  = *(const short8*)((const char*)sB + ((tb + 0)   ^ xv));
            short8 b1f = *(const short8*)((const char*)sB + ((tb + 64)  ^ xv));
            short8 b2f = *(const short8*)((const char*)sB + ((tb + 128) ^ xv));
            short8 b3f = *(const short8*)((const char*)sB + ((tb + 192) ^ xv));
            acc[tt] = __builtin_amdgcn_mfma_f32_16x16x32_bf16(a0, b0,  acc[tt], 0, 0, 0);
            acc[tt] = __builtin_amdgcn_mfma_f32_16x16x32_bf16(a1, b1f, acc[tt], 0, 0, 0);
            acc[tt] = __builtin_amdgcn_mfma_f32_16x16x32_bf16(a2, b2f, acc[tt], 0, 0, 0);
            acc[tt] = __builtin_amdgcn_mfma_f32_16x16x32_bf16(a3, b3f, acc[tt], 0, 0, 0);
        }

        if (s8 < 3) {
#pragma unroll
            for (int r = 0; r < 15; ++r) fv[r] = nf[r];
        }
    }

#pragma unroll
    for (int tt = 0; tt < 2; ++tt) {
        int spl = 16 * (2 * wv + tt) + n16;
        int e4 = spl & 7, e3 = (spl >> 3) & 3, e2 = (spl >> 5) & 1, e1 = spl >> 6;
        int o1 = bo1 + e1, o2 = bo2 + e2, o3 = bo3 + e3, o4 = e4;
#pragma unroll
        for (int r = 0; r < 4; ++r) {
            int co = hi * 4 + r;
            atomicAdd(&out[(size_t)co * 4096 + o1 * 512 + o2 * 64 + o3 * 8 + o4],
                      acc[tt][r]);
        }
    }
}

// ---------------------------------------------------------------------------
extern "C" void kernel_launch(void* const* d_in, const int* in_sizes, int n_in,
                              void* d_out, int out_size, void* d_ws, size_t ws_size,
                              hipStream_t stream) {
    const float* x  = (const float*)d_in[0];
    const float* w1 = (const float*)d_in[1];
    const float* b1 = (const float*)d_in[2];
    const float* w2 = (const float*)d_in[3];
    const float* b2 = (const float*)d_in[4];
    float* out = (float*)d_out;

    unsigned short* hpad = (unsigned short*)d_ws;        // 64*18^4 = 6,718,464 bf16
    unsigned short* w1p  = hpad + 6718464;               // 139,264 bf16
    unsigned short* w2p  = w1p + 139264;                 // 139,264 bf16

    prepack_w1<<<(16 * 64 * 136 + 255) / 256, 256, 0, stream>>>(w1, w1p);
    prepack_w2<<<(64 * 16 * 136 + 255) / 256, 256, 0, stream>>>(w2, w2p);
    zero_hpad<<<1024, 256, 0, stream>>>((uint4v*)hpad);
    out_init<<<256, 256, 0, stream>>>(b2, out);
    conv1_mfma<<<512, 256, 0, stream>>>(x, w1p, b1, hpad);
    conv2_mfma<<<512, 256, 0, stream>>>(hpad, w2p, out);
}